// Round 1
// baseline (84.570 us; speedup 1.0000x reference)
//
#include <hip/hip_runtime.h>
#include <hip/hip_bf16.h>
#include <math.h>

#define BB 256
#define TT 4096

// Cumulative feature offsets per k segment (k=2..10), nacc(k)=k*(k+1)/2
// nacc: 3,6,10,15,21,28,36,45,55 ; cumsum: 0,3,9,19,34,55,83,119,164 ; total 219
__constant__ int SEGF[10] = {0, 3, 9, 19, 34, 55, 83, 119, 164, 219};

// ---------------------------------------------------------------------------
// Kernel A: per (batch, k) block computes G = (1/T) sum_t softmax(L_t) outer
// softmax(L_t), packed as [diag(0..K-1), upper-off row-major] into ws.
// ---------------------------------------------------------------------------
template <int K>
__device__ __forceinline__ void g_accum(const float* __restrict__ L,
                                        float* __restrict__ gseg,
                                        float* __restrict__ part /* [4*55] */) {
    constexpr int NACC = K * (K + 1) / 2;
    const int b = blockIdx.x;
    const int tid = threadIdx.x;

    float acc[NACC];
#pragma unroll
    for (int i = 0; i < NACC; ++i) acc[i] = 0.f;

    const float* Lb = L + (size_t)b * TT * K;

    for (int t = tid; t < TT; t += 256) {
        const float* p = Lb + (size_t)t * K;
        float v[K];
#pragma unroll
        for (int j = 0; j < K; ++j) v[j] = p[j];

        float m = v[0];
#pragma unroll
        for (int j = 1; j < K; ++j) m = fmaxf(m, v[j]);

        float s = 0.f;
#pragma unroll
        for (int j = 0; j < K; ++j) { v[j] = __expf(v[j] - m); s += v[j]; }
        const float inv = 1.0f / s;
#pragma unroll
        for (int j = 0; j < K; ++j) v[j] *= inv;

        int idx = 0;
#pragma unroll
        for (int i = 0; i < K; ++i) {
#pragma unroll
            for (int j = i; j < K; ++j) {
                acc[idx] = fmaf(v[i], v[j], acc[idx]);
                ++idx;
            }
        }
    }

    // Block reduction: wave shuffle reduce, then 4 partials per value in LDS.
    const int lane = tid & 63;
    const int wave = tid >> 6;
#pragma unroll
    for (int i = 0; i < NACC; ++i) {
        float x = acc[i];
#pragma unroll
        for (int off = 32; off > 0; off >>= 1) x += __shfl_down(x, off, 64);
        if (lane == 0) part[wave * 55 + i] = x;
    }
    __syncthreads();

    if (tid < NACC) {
        float x = part[0 * 55 + tid] + part[1 * 55 + tid] +
                  part[2 * 55 + tid] + part[3 * 55 + tid];
        x *= (1.0f / (float)TT);
        // packed idx tid -> (i,j), j>=i
        int i = 0, rem = tid;
        while (rem >= K - i) { rem -= K - i; ++i; }
        const int j = i + rem;
        // diag-first target layout
        int tgt;
        if (j == i) tgt = i;
        else tgt = K + i * (K - 1) - (i * (i - 1)) / 2 + (j - i - 1);
        gseg[tgt] = x;
    }
}

__global__ __launch_bounds__(256) void g_kernel(
    const float* __restrict__ l2, const float* __restrict__ l3,
    const float* __restrict__ l4, const float* __restrict__ l5,
    const float* __restrict__ l6, const float* __restrict__ l7,
    const float* __restrict__ l8, const float* __restrict__ l9,
    const float* __restrict__ l10, float* __restrict__ g) {
    __shared__ float part[4 * 55];
    float* gw = g + (size_t)blockIdx.x * 219;
    switch (blockIdx.y) {
        case 0: g_accum<2>(l2, gw + 0, part); break;
        case 1: g_accum<3>(l3, gw + 3, part); break;
        case 2: g_accum<4>(l4, gw + 9, part); break;
        case 3: g_accum<5>(l5, gw + 19, part); break;
        case 4: g_accum<6>(l6, gw + 34, part); break;
        case 5: g_accum<7>(l7, gw + 55, part); break;
        case 6: g_accum<8>(l8, gw + 83, part); break;
        case 7: g_accum<9>(l9, gw + 119, part); break;
        case 8: g_accum<10>(l10, gw + 164, part); break;
    }
}

// ---------------------------------------------------------------------------
// Kernel B: per batch row — sort segments (rank sort), LayerNorm, MLP head.
// ---------------------------------------------------------------------------
__device__ __forceinline__ float gelu_exact(float x) {
    return 0.5f * x * (1.0f + erff(x * 0.70710678118654752440f));
}

__global__ __launch_bounds__(256) void head_kernel(
    const float* __restrict__ g, const float* __restrict__ gamma,
    const float* __restrict__ beta, const float* __restrict__ w1,
    const float* __restrict__ b1, const float* __restrict__ w2,
    const float* __restrict__ b2, const float* __restrict__ w3,
    const float* __restrict__ b3, float* __restrict__ out) {
    const int b = blockIdx.x;
    const int tid = threadIdx.x;

    __shared__ float pre[219];
    __shared__ float srt[219];
    __shared__ float xln[219];
    __shared__ float h1[256];
    __shared__ float h2[256];
    __shared__ float rs1[4], rs2[4];
    __shared__ float smu, srv;

    if (tid < 219) pre[tid] = g[(size_t)b * 219 + tid];
    __syncthreads();

    // Rank-based descending sort within each (diag / off) subsegment.
    if (tid < 219) {
        int ik = 0;
        while (tid >= SEGF[ik + 1]) ++ik;
        const int K = ik + 2;
        const int base = SEGF[ik];
        const int local = tid - base;
        int sstart, slen, lidx;
        if (local < K) { sstart = base; slen = K; lidx = local; }
        else { sstart = base + K; slen = (K * (K - 1)) / 2; lidx = local - K; }
        const float v = pre[tid];
        int rank = 0;
        for (int m = 0; m < slen; ++m) {
            const float u = pre[sstart + m];
            rank += (u > v) || ((u == v) && (m < lidx));
        }
        srt[sstart + rank] = v;
    }
    __syncthreads();

    // LayerNorm over the 219 features (population variance).
    const float val = (tid < 219) ? srt[tid] : 0.f;
    float s1 = val, s2 = val * val;
#pragma unroll
    for (int off = 32; off > 0; off >>= 1) {
        s1 += __shfl_down(s1, off, 64);
        s2 += __shfl_down(s2, off, 64);
    }
    const int wave = tid >> 6, lane = tid & 63;
    if (lane == 0) { rs1[wave] = s1; rs2[wave] = s2; }
    __syncthreads();
    if (tid == 0) {
        const float t1 = rs1[0] + rs1[1] + rs1[2] + rs1[3];
        const float t2 = rs2[0] + rs2[1] + rs2[2] + rs2[3];
        const float mu = t1 * (1.0f / 219.0f);
        const float var = t2 * (1.0f / 219.0f) - mu * mu;
        smu = mu;
        srv = rsqrtf(var + 1e-5f);
    }
    __syncthreads();
    if (tid < 219) xln[tid] = (srt[tid] - smu) * srv * gamma[tid] + beta[tid];
    __syncthreads();

    // Layer 1: 219 -> 256, exact GELU. Coalesced weight reads across threads.
    {
        float a = b1[tid];
#pragma unroll 8
        for (int i = 0; i < 219; ++i) a = fmaf(xln[i], w1[i * 256 + tid], a);
        h1[tid] = gelu_exact(a);
    }
    __syncthreads();

    // Layer 2: 256 -> 256, exact GELU.
    {
        float c = b2[tid];
#pragma unroll 8
        for (int i = 0; i < 256; ++i) c = fmaf(h1[i], w2[i * 256 + tid], c);
        h2[tid] = gelu_exact(c);
    }
    __syncthreads();

    // Layer 3: 256 -> 9.
    if (tid < 9) {
        float o = b3[tid];
#pragma unroll 8
        for (int i = 0; i < 256; ++i) o = fmaf(h2[i], w3[i * 9 + tid], o);
        out[(size_t)b * 9 + tid] = o;
    }
}

// ---------------------------------------------------------------------------
extern "C" void kernel_launch(void* const* d_in, const int* in_sizes, int n_in,
                              void* d_out, int out_size, void* d_ws,
                              size_t ws_size, hipStream_t stream) {
    const float* l2 = (const float*)d_in[0];
    const float* l3 = (const float*)d_in[1];
    const float* l4 = (const float*)d_in[2];
    const float* l5 = (const float*)d_in[3];
    const float* l6 = (const float*)d_in[4];
    const float* l7 = (const float*)d_in[5];
    const float* l8 = (const float*)d_in[6];
    const float* l9 = (const float*)d_in[7];
    const float* l10 = (const float*)d_in[8];
    const float* gamma = (const float*)d_in[9];
    const float* beta = (const float*)d_in[10];
    const float* w1 = (const float*)d_in[11];
    const float* b1 = (const float*)d_in[12];
    const float* w2 = (const float*)d_in[13];
    const float* b2 = (const float*)d_in[14];
    const float* w3 = (const float*)d_in[15];
    const float* b3 = (const float*)d_in[16];

    float* gbuf = (float*)d_ws;  // [256][219] floats = 224 KB
    float* outp = (float*)d_out;

    dim3 gridA(BB, 9);
    g_kernel<<<gridA, 256, 0, stream>>>(l2, l3, l4, l5, l6, l7, l8, l9, l10,
                                        gbuf);
    head_kernel<<<BB, 256, 0, stream>>>(gbuf, gamma, beta, w1, b1, w2, b2, w3,
                                        b3, outp);
}